// Round 8
// baseline (1359.284 us; speedup 1.0000x reference)
//
#include <hip/hip_runtime.h>
#include <hip/hip_bf16.h>
#include <hip/hip_fp16.h>
#include <cstdint>
#include <cstddef>

#define NB   131072   // items
#define ED   256      // e_dim
#define NQL  4        // levels
#define NEC  256      // codebook entries

typedef _Float16 f16;
typedef f16  f16x8 __attribute__((ext_vector_type(8)));
typedef float f32x4 __attribute__((ext_vector_type(4)));

static constexpr float FMAXV = 3.402823466e+38f;
static constexpr float TAU   = 0.15625f;   // rescore gate on approx top-2 gap

static constexpr size_t OFF_REC  = (size_t)NB * ED;
static constexpr size_t OFF_LOSS = 2 * (size_t)NB * ED;
static constexpr size_t OFF_SIDX = OFF_LOSS + 1;
static constexpr size_t OFF_RIDX = OFF_SIDX + (size_t)NB * NQL;

// workspace layout (bytes)
static constexpr size_t WS_LOSS = 0;                      // 8 doubles
static constexpr size_t WS_NORM = 256;                    // 8*256 f32 (norm - 256)
static constexpr size_t WS_CBH  = 256 + 8 * 256 * 4;      // 8448; 8*256*256 f16 (1 MB)

// ---- prep: zero loss accumulator + codebook row norms (pre-shifted by -256) ----
__global__ void kPrep(const float* __restrict__ cbS, const float* __restrict__ cbR,
                      float* __restrict__ norms, double* __restrict__ lossAcc) {
  const int cbi = blockIdx.x;    // 0..7
  const int j   = threadIdx.x;   // 0..255
  if (cbi == 0 && j < 8) lossAcc[j] = 0.0;
  const float* row = (cbi < 4 ? cbS : cbR) + ((size_t)(cbi & 3) * NEC + j) * ED;
  float acc = 0.f;
  for (int k = 0; k < ED; k += 4) {
    float4 v = *(const float4*)(row + k);
    acc += v.x * v.x + v.y * v.y + v.z * v.z + v.w * v.w;
  }
  norms[cbi * NEC + j] = acc - 256.0f;   // exact shift (Sterbenz range)
}

// ---- f16 copy of codebooks (natural [cbi][j][k] layout) ----
__global__ void kConvH(const float* __restrict__ cbS, const float* __restrict__ cbR,
                       f16* __restrict__ cbH) {
  const int f   = blockIdx.x * 256 + threadIdx.x;   // 0..524287
  const int cbi = f >> 16;
  const int rem = f & 65535;
  const float v = (cbi < 4 ? cbS + ((size_t)cbi << 16) : cbR + ((size_t)(cbi - 4) << 16))[rem];
  cbH[f] = (f16)v;   // RTN
}

// packed key helpers: low 8 mantissa bits carry the codeword index
__device__ __forceinline__ float pk(float v, int j) {
  return __uint_as_float((__float_as_uint(v) & ~255u) | (unsigned)j);
}
__device__ __forceinline__ float unpv(float k) {
  return __uint_as_float(__float_as_uint(k) & ~255u);
}
__device__ __forceinline__ void ins3(float& s0, float& s1, float& s2, float k) {
  float t0 = fmaxf(s0, k); s0 = fminf(s0, k);
  float t1 = fmaxf(s1, t0); s1 = fminf(s1, t0);
  s2 = fminf(s2, t1);
}
__device__ __forceinline__ void mrg3(float& a0, float& a1, float& a2,
                                     float b0, float b1, float b2) {
  float x  = fmaxf(a0, b0);
  float c0 = fminf(a0, b0);
  float m1 = fminf(a1, b1), M1 = fmaxf(a1, b1);
  float c1 = fminf(fminf(x, a1), b1);
  float c2 = fminf(fminf(fmaxf(x, m1), M1), fminf(a2, b2));
  a0 = c0; a1 = c1; a2 = c2;
}

// ---- main fused RVQ kernel: BARRIER-FREE waves, register-budgeted ----
// Each wave owns 16 items end-to-end (private Rh region, in-wave argmin/update;
// zero __syncthreads in the level chain). gfx950 unified VGPR/AGPR budget at
// bounds(256,3) is 170 TOTAL: j-space in 4 passes of 64 (acc[4]=16 AGPR,
// Bf[4]=16 VGPR, x2 unroll) keeps demand ~150 -> no spill (round 7's 2x128
// passes demanded ~185 -> spilled res to scratch, VGPR_Count=84, +350MB WRITE).
__global__ __launch_bounds__(256, 3)
void kMain(const float* __restrict__ x,
           const float* __restrict__ cbS,
           const float* __restrict__ cbR,
           const f16*  __restrict__ cbH,
           const float* __restrict__ norms,
           double* __restrict__ lossAcc,
           float* __restrict__ out) {
  __shared__ __align__(16) char  RhBuf[64 * 512];      // 4 waves x 16 items x 512B (32 KB)
  __shared__ float redS[4];

  const int tid   = threadIdx.x;
  const int lane  = tid & 63;
  const int w     = tid >> 6;
  const int it_o  = tid >> 2;       // block-local item 0..63 (wave w owns 16w..16w+15)
  const int kq    = tid & 3;        // k-quarter within owner quad
  const int b0    = blockIdx.x * 64;
  const int l15   = lane & 15;      // item within wave (GEMM/argmin view)
  const int l4    = lane >> 4;      // k-slot / j-subgroup

  float res[64];
  float lossReg = 0.f;

#pragma unroll 1
  for (int br = 0; br < 2; ++br) {
    const float* cbf32 = br ? cbR : cbS;

    // load residual = x[:, br*E .. br*E+E) slice into registers
    {
      const float* xp = x + (size_t)(b0 + it_o) * (2 * ED) + br * ED + kq * 64;
#pragma unroll
      for (int i = 0; i < 16; ++i) {
        float4 v = *(const float4*)(xp + 4 * i);
        res[4 * i + 0] = v.x; res[4 * i + 1] = v.y;
        res[4 * i + 2] = v.z; res[4 * i + 3] = v.w;
      }
    }

#pragma unroll 1
    for (int lev = 0; lev < NQL; ++lev) {
      const int cbi = br * 4 + lev;
      const float* nrm = norms + (size_t)cbi * NEC;
      const f16*   cbh = cbH + ((size_t)cbi << 16);

      // convert res -> Rh (f16, RTN), own item's row (wave-private region)
#pragma unroll
      for (int c = 0; c < 8; ++c) {
        f16x8 h;
#pragma unroll
        for (int u = 0; u < 8; ++u) h[u] = (f16)res[c * 8 + u];
        int off = it_o * 512 + kq * 128 + c * 16;
        off ^= (it_o & 7) << 4;
        *(f16x8*)&RhBuf[off] = h;
      }
      // no barrier: readers are lanes of the SAME wave (in-order DS + lgkmcnt)

      float s0 = FMAXV, s1 = FMAXV, s2 = FMAXV;   // running top-3 packed keys

#pragma unroll 1
      for (int p = 0; p < 4; ++p) {               // j-quarters: 64 codewords each
        f32x4 acc[4];
#pragma unroll
        for (int nt = 0; nt < 4; ++nt) { f32x4 z = {0.f, 0.f, 0.f, 0.f}; acc[nt] = z; }

#pragma unroll 2
        for (int ks = 0; ks < 8; ++ks) {
          const int it = w * 16 + l15;
          // XOR on the FULL offset (matches write side) — do not hoist.
          const int offA = (it * 512 + ks * 64 + l4 * 16) ^ ((l15 & 7) << 4);
          const f16x8 A = *(const f16x8*)&RhBuf[offA];
          f16x8 Bf[4];
#pragma unroll
          for (int nt = 0; nt < 4; ++nt) {
            const int j = p * 64 + nt * 16 + l15;
            Bf[nt] = *(const f16x8*)&cbh[(size_t)j * ED + ks * 32 + l4 * 8];
          }
#pragma unroll
          for (int nt = 0; nt < 4; ++nt)
            // operand swap: codebook rows as A-operand -> D[j][item]
            acc[nt] = __builtin_amdgcn_mfma_f32_16x16x32_f16(Bf[nt], A, acc[nt], 0, 0, 0);
        }

        // fold this quarter's 16 per-lane keys into the running top-3
#pragma unroll
        for (int nt = 0; nt < 4; ++nt) {
          const float4 nv4 = *(const float4*)&nrm[p * 64 + nt * 16 + l4 * 4];
#pragma unroll
          for (int r = 0; r < 4; ++r) {
            const int j = p * 64 + nt * 16 + l4 * 4 + r;
            const float nr = (r == 0 ? nv4.x : r == 1 ? nv4.y : r == 2 ? nv4.z : nv4.w);
            ins3(s0, s1, s2, pk(fmaf(-2.f, acc[nt][r], nr), j));
          }
        }
      }

      // merge the 4 l4-groups (disjoint j-subsets, same item l15): xor 16, 32
      {
        float b0k = __shfl_xor(s0, 16), b1k = __shfl_xor(s1, 16), b2k = __shfl_xor(s2, 16);
        mrg3(s0, s1, s2, b0k, b1k, b2k);
        b0k = __shfl_xor(s0, 32); b1k = __shfl_xor(s1, 32); b2k = __shfl_xor(s2, 32);
        mrg3(s0, s1, s2, b0k, b1k, b2k);
      }
      // redistribute: res-owner lane L (item L>>2) fetches item-(L>>2)'s triple
      s0 = __shfl(s0, lane >> 2);
      s1 = __shfl(s1, lane >> 2);
      s2 = __shfl(s2, lane >> 2);

      int jm = (int)(__float_as_uint(s0) & 255u);
      const float gap = unpv(s1) - unpv(s0);
      if (gap < TAU) {   // quad-uniform: exact fp32 rescore of top-3
        const int cand[3] = { jm,
                              (int)(__float_as_uint(s1) & 255u),
                              (int)(__float_as_uint(s2) & 255u) };
        float bestd = FMAXV; int bestj = 0;
#pragma unroll 1
        for (int cc = 0; cc < 3; ++cc) {
          const int j = cand[cc];
          const float* row = cbf32 + ((size_t)lev * NEC + j) * ED + kq * 64;
          float p2 = 0.f;
#pragma unroll
          for (int i = 0; i < 16; ++i) {
            float4 q = *(const float4*)(row + 4 * i);
            p2 = fmaf(res[4 * i + 0], q.x, p2);
            p2 = fmaf(res[4 * i + 1], q.y, p2);
            p2 = fmaf(res[4 * i + 2], q.z, p2);
            p2 = fmaf(res[4 * i + 3], q.w, p2);
          }
          p2 += __shfl_xor(p2, 1);
          p2 += __shfl_xor(p2, 2);
          const float d = fmaf(-2.f, p2, nrm[j]);
          if (d < bestd || (d == bestd && j < bestj)) { bestd = d; bestj = j; }
        }
        jm = bestj;
      }
      if (kq == 0) {
        const size_t ioff = (br ? OFF_RIDX : OFF_SIDX) + (size_t)(b0 + it_o) * NQL + lev;
        out[ioff] = (float)jm;
      }

      // ---- residual update + loss (exact reference rounding chain) ----
      {
        const float* crow = cbf32 + ((size_t)lev * NEC + jm) * ED + kq * 64;
#pragma unroll
        for (int i = 0; i < 16; ++i) {
          float4 q = *(const float4*)(crow + 4 * i);
#pragma unroll
          for (int u = 0; u < 4; ++u) {
            float cv = (u == 0 ? q.x : u == 1 ? q.y : u == 2 ? q.z : q.w);
            float r  = res[4 * i + u];
            float dd = cv - r;
            lossReg = fmaf(dd, dd, lossReg);
            float xr = r + dd;      // straight-through x_res
            res[4 * i + u] = r - xr;
          }
        }
      }
    }

    // x_q = x - res_final
    {
      const float* xp = x + (size_t)(b0 + it_o) * (2 * ED) + br * ED + kq * 64;
      float* op = out + (br ? OFF_REC : 0) + (size_t)(b0 + it_o) * ED + kq * 64;
#pragma unroll
      for (int i = 0; i < 16; ++i) {
        float4 xv = *(const float4*)(xp + 4 * i);
        float4 o;
        o.x = xv.x - res[4 * i + 0];
        o.y = xv.y - res[4 * i + 1];
        o.z = xv.z - res[4 * i + 2];
        o.w = xv.w - res[4 * i + 3];
        *(float4*)(op + 4 * i) = o;
      }
    }
  }

  // ---- loss: one wave-reduce, single barrier at kernel end, one atomic ----
#pragma unroll
  for (int d = 1; d < 64; d <<= 1) lossReg += __shfl_xor(lossReg, d);
  if (lane == 0) redS[w] = lossReg;
  __syncthreads();
  if (tid == 0)
    atomicAdd(&lossAcc[0], (double)((redS[0] + redS[1]) + (redS[2] + redS[3])));
}

// ---- finalize scalar loss ----
__global__ void kFin(const double* __restrict__ lossAcc, float* __restrict__ out) {
  if (blockIdx.x == 0 && threadIdx.x == 0) {
    out[OFF_LOSS] = (float)(lossAcc[0] * 1.25 / ((double)NB * ED) / 8.0);
  }
}

extern "C" void kernel_launch(void* const* d_in, const int* in_sizes, int n_in,
                              void* d_out, int out_size, void* d_ws, size_t ws_size,
                              hipStream_t stream) {
  const float* x   = (const float*)d_in[0];
  const float* cbS = (const float*)d_in[1];
  const float* cbR = (const float*)d_in[2];
  float* out = (float*)d_out;
  char*  ws  = (char*)d_ws;

  double* lossAcc = (double*)(ws + WS_LOSS);
  float*  norms   = (float*)(ws + WS_NORM);
  f16*    cbH     = (f16*)(ws + WS_CBH);

  hipLaunchKernelGGL(kPrep,  dim3(8),    dim3(256), 0, stream, cbS, cbR, norms, lossAcc);
  hipLaunchKernelGGL(kConvH, dim3(2048), dim3(256), 0, stream, cbS, cbR, cbH);
  hipLaunchKernelGGL(kMain,  dim3(NB / 64), dim3(256), 0, stream,
                     x, cbS, cbR, cbH, norms, lossAcc, out);
  hipLaunchKernelGGL(kFin,   dim3(1),    dim3(64),  0, stream, lossAcc, out);
}

// Round 9
// 735.605 us; speedup vs baseline: 1.8478x; 1.8478x over previous
//
#include <hip/hip_runtime.h>
#include <hip/hip_bf16.h>
#include <hip/hip_fp16.h>
#include <cstdint>
#include <cstddef>

#define NB   131072   // items
#define ED   256      // e_dim
#define NQL  4        // levels
#define NEC  256      // codebook entries

typedef _Float16 f16;
typedef f16  f16x8 __attribute__((ext_vector_type(8)));
typedef float f32x4 __attribute__((ext_vector_type(4)));

static constexpr float FMAXV = 3.402823466e+38f;
static constexpr float TAU   = 0.15625f;   // rescore gate on approx top-2 gap

static constexpr size_t OFF_REC  = (size_t)NB * ED;
static constexpr size_t OFF_LOSS = 2 * (size_t)NB * ED;
static constexpr size_t OFF_SIDX = OFF_LOSS + 1;
static constexpr size_t OFF_RIDX = OFF_SIDX + (size_t)NB * NQL;

// workspace layout (bytes)
static constexpr size_t WS_LOSS = 0;                      // 8 doubles
static constexpr size_t WS_NORM = 256;                    // 8*256 f32 (norm - 256)
static constexpr size_t WS_CBH  = 256 + 8 * 256 * 4;      // 8448; 8*256*256 f16 (1 MB)

// ---- prep: zero loss accumulator + codebook row norms (pre-shifted by -256) ----
__global__ void kPrep(const float* __restrict__ cbS, const float* __restrict__ cbR,
                      float* __restrict__ norms, double* __restrict__ lossAcc) {
  const int cbi = blockIdx.x;    // 0..7
  const int j   = threadIdx.x;   // 0..255
  if (cbi == 0 && j < 8) lossAcc[j] = 0.0;
  const float* row = (cbi < 4 ? cbS : cbR) + ((size_t)(cbi & 3) * NEC + j) * ED;
  float acc = 0.f;
  for (int k = 0; k < ED; k += 4) {
    float4 v = *(const float4*)(row + k);
    acc += v.x * v.x + v.y * v.y + v.z * v.z + v.w * v.w;
  }
  norms[cbi * NEC + j] = acc - 256.0f;   // exact shift (Sterbenz range)
}

// ---- f16 copy of codebooks (natural [cbi][j][k] layout) ----
__global__ void kConvH(const float* __restrict__ cbS, const float* __restrict__ cbR,
                       f16* __restrict__ cbH) {
  const int f   = blockIdx.x * 256 + threadIdx.x;   // 0..524287
  const int cbi = f >> 16;
  const int rem = f & 65535;
  const float v = (cbi < 4 ? cbS + ((size_t)cbi << 16) : cbR + ((size_t)(cbi - 4) << 16))[rem];
  cbH[f] = (f16)v;   // RTN
}

// packed key helpers: low 8 mantissa bits carry the codeword index
__device__ __forceinline__ float pk(float v, int j) {
  return __uint_as_float((__float_as_uint(v) & ~255u) | (unsigned)j);
}
__device__ __forceinline__ float unpv(float k) {
  return __uint_as_float(__float_as_uint(k) & ~255u);
}
__device__ __forceinline__ void ins3(float& s0, float& s1, float& s2, float k) {
  float t0 = fmaxf(s0, k); s0 = fminf(s0, k);
  float t1 = fmaxf(s1, t0); s1 = fminf(s1, t0);
  s2 = fminf(s2, t1);
}
__device__ __forceinline__ void mrg3(float& a0, float& a1, float& a2,
                                     float b0, float b1, float b2) {
  float x  = fmaxf(a0, b0);
  float c0 = fminf(a0, b0);
  float m1 = fminf(a1, b1), M1 = fmaxf(a1, b1);
  float c1 = fminf(fminf(x, a1), b1);
  float c2 = fminf(fminf(fmaxf(x, m1), M1), fminf(a2, b2));
  a0 = c0; a1 = c1; a2 = c2;
}

// ---- main fused RVQ kernel: 32 items/block, 8 threads/item, 3 blocks/CU ----
// gfx950 allocator at min-waves=3 splits the 170-reg unified budget ~84 VGPR
// + ~84 AGPR (rounds 5/7/8 all showed VGPR_Count=84). So the NON-accumulator
// working set must fit 84 arch VGPRs: res[32] + A[2](8) + Bf[4](16, ks
// unroll 1) + ~25 misc = ~81. acc[2][4] = 32 AGPR. 12 waves/CU (1.5x round 6)
// for latency hiding; B re-read 2x vs round 6 (L2-resident, ~4.3 GB).
__global__ __launch_bounds__(256, 3)
void kMain(const float* __restrict__ x,
           const float* __restrict__ cbS,
           const float* __restrict__ cbR,
           const f16*  __restrict__ cbH,
           const float* __restrict__ norms,
           double* __restrict__ lossAcc,
           float* __restrict__ out) {
  __shared__ __align__(16) char  RhBuf[32 * 512];      // 32 items x 512B f16 (16 KB)
  __shared__ __align__(16) float keybuf[32][4][4];     // per-wave top-3 per item (2 KB)
  __shared__ float redS[4];

  const int tid   = threadIdx.x;
  const int lane  = tid & 63;
  const int w     = tid >> 6;       // wave: owns codewords [64w, 64w+64)
  const int it_o  = tid >> 3;       // owner item 0..31 (8 threads per item)
  const int kg    = tid & 7;        // k-chunk (32 floats) within owner group
  const int b0    = blockIdx.x * 32;
  const int l15   = lane & 15;
  const int l4    = lane >> 4;

  float res[32];
  float lossReg = 0.f;

#pragma unroll 1
  for (int br = 0; br < 2; ++br) {
    const float* cbf32 = br ? cbR : cbS;

    // load residual = x[:, br*E .. br*E+E) slice into registers (32 f32/thread)
    {
      const float* xp = x + (size_t)(b0 + it_o) * (2 * ED) + br * ED + kg * 32;
#pragma unroll
      for (int i = 0; i < 8; ++i) {
        float4 v = *(const float4*)(xp + 4 * i);
        res[4 * i + 0] = v.x; res[4 * i + 1] = v.y;
        res[4 * i + 2] = v.z; res[4 * i + 3] = v.w;
      }
    }

#pragma unroll 1
    for (int lev = 0; lev < NQL; ++lev) {
      const int cbi = br * 4 + lev;
      const float* nrm = norms + (size_t)cbi * NEC;
      const f16*   cbh = cbH + ((size_t)cbi << 16);

      // convert res -> Rh (f16, RTN), own 64B slice of item's 512B row
#pragma unroll
      for (int c = 0; c < 4; ++c) {
        f16x8 h;
#pragma unroll
        for (int u = 0; u < 8; ++u) h[u] = (f16)res[c * 8 + u];
        int off = it_o * 512 + kg * 64 + c * 16;
        off ^= (it_o & 7) << 4;
        *(f16x8*)&RhBuf[off] = h;
      }
      __syncthreads();   // barrier 1: Rh ready

      // ---- GEMM: 32(item) x 64(j) per wave, D[j][item], acc[2][4] ----
      f32x4 acc[2][4];
#pragma unroll
      for (int mt = 0; mt < 2; ++mt)
#pragma unroll
        for (int nt = 0; nt < 4; ++nt) { f32x4 z = {0.f, 0.f, 0.f, 0.f}; acc[mt][nt] = z; }

#pragma unroll 1
      for (int ks = 0; ks < 8; ++ks) {
        f16x8 A[2], Bf[4];
#pragma unroll
        for (int mt = 0; mt < 2; ++mt) {
          const int it = mt * 16 + l15;
          // XOR on the FULL offset (matches write side) — do not hoist.
          const int offA = (it * 512 + ks * 64 + l4 * 16) ^ ((it & 7) << 4);
          A[mt] = *(const f16x8*)&RhBuf[offA];
        }
#pragma unroll
        for (int nt = 0; nt < 4; ++nt) {
          const int j = w * 64 + nt * 16 + l15;
          Bf[nt] = *(const f16x8*)&cbh[(size_t)j * ED + ks * 32 + l4 * 8];
        }
#pragma unroll
        for (int mt = 0; mt < 2; ++mt)
#pragma unroll
          for (int nt = 0; nt < 4; ++nt)
            // operand swap: codebook rows as A-operand -> D[j][item]
            acc[mt][nt] = __builtin_amdgcn_mfma_f32_16x16x32_f16(Bf[nt], A[mt], acc[mt][nt], 0, 0, 0);
      }

      // ---- argmin: per mt, lane holds 16 j-keys for item mt*16+l15 ----
#pragma unroll
      for (int mt = 0; mt < 2; ++mt) {
        float s0 = FMAXV, s1 = FMAXV, s2 = FMAXV;
#pragma unroll
        for (int nt = 0; nt < 4; ++nt) {
          const float4 nv4 = *(const float4*)&nrm[w * 64 + nt * 16 + l4 * 4];
#pragma unroll
          for (int r = 0; r < 4; ++r) {
            const int j = w * 64 + nt * 16 + l4 * 4 + r;
            const float nr = (r == 0 ? nv4.x : r == 1 ? nv4.y : r == 2 ? nv4.z : nv4.w);
            ins3(s0, s1, s2, pk(fmaf(-2.f, acc[mt][nt][r], nr), j));
          }
        }
        // merge the 4 l4-groups (disjoint j-subsets, same item): xor 16, 32
        {
          float b0k = __shfl_xor(s0, 16), b1k = __shfl_xor(s1, 16), b2k = __shfl_xor(s2, 16);
          mrg3(s0, s1, s2, b0k, b1k, b2k);
          b0k = __shfl_xor(s0, 32); b1k = __shfl_xor(s1, 32); b2k = __shfl_xor(s2, 32);
          mrg3(s0, s1, s2, b0k, b1k, b2k);
        }
        if (l4 == 0) {   // lanes 0..15 write item mt*16+l15
          float4 v; v.x = s0; v.y = s1; v.z = s2; v.w = FMAXV;
          *(float4*)&keybuf[mt * 16 + l15][w][0] = v;
        }
      }
      __syncthreads();   // barrier 2: keybuf ready (also: Rh reads done)

      // ---- cross-wave merge in the 8-thread owner group ----
      int jm;
      {
        const int kq4 = kg & 3;
        float4 v = *(const float4*)&keybuf[it_o][kq4][0];
        float s0 = v.x, s1 = v.y, s2 = v.z;
        {
          float b0k = __shfl_xor(s0, 1), b1k = __shfl_xor(s1, 1), b2k = __shfl_xor(s2, 1);
          mrg3(s0, s1, s2, b0k, b1k, b2k);
          b0k = __shfl_xor(s0, 2); b1k = __shfl_xor(s1, 2); b2k = __shfl_xor(s2, 2);
          mrg3(s0, s1, s2, b0k, b1k, b2k);
        }
        jm = (int)(__float_as_uint(s0) & 255u);
        const float gap = unpv(s1) - unpv(s0);
        if (gap < TAU) {   // group-uniform: exact fp32 rescore of top-3
          const int cand[3] = { jm,
                                (int)(__float_as_uint(s1) & 255u),
                                (int)(__float_as_uint(s2) & 255u) };
          float bestd = FMAXV; int bestj = 0;
#pragma unroll 1
          for (int cc = 0; cc < 3; ++cc) {
            const int j = cand[cc];
            const float* row = cbf32 + ((size_t)lev * NEC + j) * ED + kg * 32;
            float p2 = 0.f;
#pragma unroll
            for (int i = 0; i < 8; ++i) {
              float4 q = *(const float4*)(row + 4 * i);
              p2 = fmaf(res[4 * i + 0], q.x, p2);
              p2 = fmaf(res[4 * i + 1], q.y, p2);
              p2 = fmaf(res[4 * i + 2], q.z, p2);
              p2 = fmaf(res[4 * i + 3], q.w, p2);
            }
            p2 += __shfl_xor(p2, 1);
            p2 += __shfl_xor(p2, 2);
            p2 += __shfl_xor(p2, 4);
            const float d = fmaf(-2.f, p2, nrm[j]);
            if (d < bestd || (d == bestd && j < bestj)) { bestd = d; bestj = j; }
          }
          jm = bestj;
        }
        if (kg == 0) {
          const size_t ioff = (br ? OFF_RIDX : OFF_SIDX) + (size_t)(b0 + it_o) * NQL + lev;
          out[ioff] = (float)jm;
        }
      }

      // ---- residual update + loss (exact reference rounding chain) ----
      {
        const float* crow = cbf32 + ((size_t)lev * NEC + jm) * ED + kg * 32;
#pragma unroll
        for (int i = 0; i < 8; ++i) {
          float4 q = *(const float4*)(crow + 4 * i);
#pragma unroll
          for (int u = 0; u < 4; ++u) {
            float cv = (u == 0 ? q.x : u == 1 ? q.y : u == 2 ? q.z : q.w);
            float r  = res[4 * i + u];
            float dd = cv - r;
            lossReg = fmaf(dd, dd, lossReg);
            float xr = r + dd;      // straight-through x_res
            res[4 * i + u] = r - xr;
          }
        }
      }
    }

    // x_q = x - res_final
    {
      const float* xp = x + (size_t)(b0 + it_o) * (2 * ED) + br * ED + kg * 32;
      float* op = out + (br ? OFF_REC : 0) + (size_t)(b0 + it_o) * ED + kg * 32;
#pragma unroll
      for (int i = 0; i < 8; ++i) {
        float4 xv = *(const float4*)(xp + 4 * i);
        float4 o;
        o.x = xv.x - res[4 * i + 0];
        o.y = xv.y - res[4 * i + 1];
        o.z = xv.z - res[4 * i + 2];
        o.w = xv.w - res[4 * i + 3];
        *(float4*)(op + 4 * i) = o;
      }
    }
    __syncthreads();  // RhBuf reused by next branch
  }

  // ---- loss: one wave-reduce + one atomic per block, once per kernel ----
#pragma unroll
  for (int d = 1; d < 64; d <<= 1) lossReg += __shfl_xor(lossReg, d);
  if (lane == 0) redS[w] = lossReg;
  __syncthreads();
  if (tid == 0)
    atomicAdd(&lossAcc[0], (double)((redS[0] + redS[1]) + (redS[2] + redS[3])));
}

// ---- finalize scalar loss ----
__global__ void kFin(const double* __restrict__ lossAcc, float* __restrict__ out) {
  if (blockIdx.x == 0 && threadIdx.x == 0) {
    out[OFF_LOSS] = (float)(lossAcc[0] * 1.25 / ((double)NB * ED) / 8.0);
  }
}

extern "C" void kernel_launch(void* const* d_in, const int* in_sizes, int n_in,
                              void* d_out, int out_size, void* d_ws, size_t ws_size,
                              hipStream_t stream) {
  const float* x   = (const float*)d_in[0];
  const float* cbS = (const float*)d_in[1];
  const float* cbR = (const float*)d_in[2];
  float* out = (float*)d_out;
  char*  ws  = (char*)d_ws;

  double* lossAcc = (double*)(ws + WS_LOSS);
  float*  norms   = (float*)(ws + WS_NORM);
  f16*    cbH     = (f16*)(ws + WS_CBH);

  hipLaunchKernelGGL(kPrep,  dim3(8),    dim3(256), 0, stream, cbS, cbR, norms, lossAcc);
  hipLaunchKernelGGL(kConvH, dim3(2048), dim3(256), 0, stream, cbS, cbR, cbH);
  hipLaunchKernelGGL(kMain,  dim3(NB / 32), dim3(256), 0, stream,
                     x, cbS, cbR, cbH, norms, lossAcc, out);
  hipLaunchKernelGGL(kFin,   dim3(1),    dim3(64),  0, stream, lossAcc, out);
}